// Round 3
// baseline (730.131 us; speedup 1.0000x reference)
//
#include <hip/hip_runtime.h>

#define T_STEPS 120
#define NF_IN   180
#define H_DIM   128
#define G_DIM   512
#define K_FC    192
#define HP      136   // h_lds row stride (shorts)
#define XPR     12    // xp/racc row stride (floats): b128-aligned, low-conflict

typedef __attribute__((ext_vector_type(8))) short short8;
typedef __attribute__((ext_vector_type(4))) float f32x4;

__device__ __forceinline__ f32x4 mfma16(short8 a, short8 b, f32x4 c) {
    return __builtin_amdgcn_mfma_f32_16x16x32_bf16(a, b, c, 0, 0, 0);
}

__device__ __forceinline__ short f2bf(float x) {
    union { float f; unsigned u; } v; v.f = x;
    unsigned r = v.u + 0x7fffu + ((v.u >> 16) & 1u);
    return (short)(r >> 16);
}

// gates arrive pre-scaled: i,f,o rows of W,b were multiplied by -1 (so
// sigmoid(x) = rcp(1+exp(y)) with y the matmul output), g rows by +2
// (so tanh(x) = 1 - 2*rcp(1+exp(y))).
__device__ __forceinline__ float sig_y(float y) {
    return __builtin_amdgcn_rcpf(1.f + __expf(y));
}
__device__ __forceinline__ float tanh_y(float y) {
    return 1.f - 2.f * __builtin_amdgcn_rcpf(1.f + __expf(y));
}

// ---------------- K1: weight prep (BN fold + bf16 + gate-sign folding) -------
__global__ void prep_kernel(
    const float* __restrict__ fc_w, const float* __restrict__ fc_b,
    const float* __restrict__ bn_g, const float* __restrict__ bn_b,
    const float* __restrict__ bn_mean, const float* __restrict__ bn_var,
    const float* __restrict__ wih0, const float* __restrict__ whh0,
    const float* __restrict__ bih0, const float* __restrict__ bhh0,
    const float* __restrict__ wih1, const float* __restrict__ whh1,
    const float* __restrict__ bih1, const float* __restrict__ bhh1,
    short* __restrict__ fcw_o, float* __restrict__ fcb_o,
    float* __restrict__ bias0_o, float* __restrict__ bias1_o,
    short* __restrict__ wih0_o, short* __restrict__ whh0_o,
    short* __restrict__ wih1_o, short* __restrict__ whh1_o)
{
    int tid = blockIdx.x * blockDim.x + threadIdx.x;
    int stride = gridDim.x * blockDim.x;
    for (int i = tid; i < H_DIM * K_FC; i += stride) {
        int h = i / K_FC, f = i % K_FC;
        float s = bn_g[h] * rsqrtf(bn_var[h] + 1e-5f);
        float v = (f < NF_IN) ? fc_w[h * NF_IN + f] * s : 0.f;
        fcw_o[i] = f2bf(v);
    }
    for (int i = tid; i < H_DIM; i += stride) {
        float s = bn_g[i] * rsqrtf(bn_var[i] + 1e-5f);
        fcb_o[i] = (fc_b[i] - bn_mean[i]) * s + bn_b[i];
    }
    for (int i = tid; i < G_DIM; i += stride) {
        float sc = ((i >> 7) == 2) ? 2.f : -1.f;   // gate g:+2, i/f/o:-1
        bias0_o[i] = (bih0[i] + bhh0[i]) * sc;
        bias1_o[i] = (bih1[i] + bhh1[i]) * sc;
    }
    for (int i = tid; i < G_DIM * H_DIM; i += stride) {
        float sc = ((i >> 7) / H_DIM == 2) ? 2.f : -1.f;  // row = i/H_DIM; row>>7
        wih0_o[i] = f2bf(wih0[i] * sc); whh0_o[i] = f2bf(whh0[i] * sc);
        wih1_o[i] = f2bf(wih1[i] * sc); whh1_o[i] = f2bf(whh1[i] * sc);
    }
}

// ---------------- K2: fused FC + BN + LeakyReLU (unchanged) ------------------
__global__ __launch_bounds__(256) void fc_kernel(
    const float* __restrict__ x, const short* __restrict__ fcw,
    const float* __restrict__ fcb, short* __restrict__ xfc)
{
    __shared__ short outs[120 * 132];
    const int b = blockIdx.x;
    const int tid = threadIdx.x;
    const int wave = tid >> 6, lane = tid & 63;
    const int m16 = lane & 15, q = lane >> 4;

    short8 af[2][6];
#pragma unroll
    for (int mi = 0; mi < 2; ++mi) {
        int t = (wave * 2 + mi) * 16 + m16;
        if (t > 119) t = 119;
        const float* xb = x + (size_t)b * (NF_IN * T_STEPS) + (size_t)q * 8 * T_STEPS + t;
#pragma unroll
        for (int kc = 0; kc < 6; ++kc) {
            union { short s[8]; short8 v; } u;
#pragma unroll
            for (int j = 0; j < 8; ++j) {
                int f = kc * 32 + q * 8 + j;
                float val = (f < NF_IN) ? xb[(kc * 32 + j) * T_STEPS] : 0.f;
                u.s[j] = f2bf(val);
            }
            af[mi][kc] = u.v;
        }
    }

    float fcb_v[8];
#pragma unroll
    for (int nt = 0; nt < 8; ++nt) fcb_v[nt] = fcb[nt * 16 + m16];

    f32x4 acc[2][8];
#pragma unroll
    for (int mi = 0; mi < 2; ++mi)
#pragma unroll
        for (int nt = 0; nt < 8; ++nt) acc[mi][nt] = (f32x4){0.f, 0.f, 0.f, 0.f};

#pragma unroll
    for (int nt = 0; nt < 8; ++nt) {
        short8 bf[6];
#pragma unroll
        for (int kc = 0; kc < 6; ++kc)
            bf[kc] = *(const short8*)(fcw + (nt * 16 + m16) * K_FC + kc * 32 + q * 8);
#pragma unroll
        for (int mi = 0; mi < 2; ++mi)
#pragma unroll
            for (int kc = 0; kc < 6; ++kc)
                acc[mi][nt] = mfma16(af[mi][kc], bf[kc], acc[mi][nt]);
    }

#pragma unroll
    for (int mi = 0; mi < 2; ++mi)
#pragma unroll
        for (int nt = 0; nt < 8; ++nt)
#pragma unroll
            for (int r = 0; r < 4; ++r) {
                int t = (wave * 2 + mi) * 16 + q * 4 + r;
                int h = nt * 16 + m16;
                float v = acc[mi][nt][r] + fcb_v[nt];
                v = (v >= 0.f) ? v : 0.01f * v;
                if (t < 120) outs[t * 132 + h] = f2bf(v);
            }
    __syncthreads();

    unsigned* dst = (unsigned*)xfc + (size_t)b * (T_STEPS * H_DIM / 2);
    const unsigned* srcs = (const unsigned*)outs;
    for (int i = tid; i < T_STEPS * H_DIM / 2; i += 256) {
        int t = i >> 6, c2 = i & 63;
        dst[i] = srcs[t * 66 + c2];
    }
}

// ---------------- K3: one LSTM layer, symmetric waves ------------------------
// grid = B/8, 512 threads = 8 waves. Wave w owns h-dims [16w,16w+16) of BOTH
// matmuls (whh-slice + wih-slice in VGPRs) and updates its own 16 dims x 8
// rows (2 elems/lane, full 64-lane utilization). racc/xp slices are produced
// and consumed by the SAME wave -> redistribution via per-wave LDS scratch
// needs no barrier. Exactly one __syncthreads per step (protects h_lds only).
__global__ __launch_bounds__(512, 2) void lstm_kernel(
    const short* h_in,               // (B,T,128) bf16
    const short* __restrict__ wih,   // (512,128) bf16, gate-sign folded
    const short* __restrict__ whh,   // (512,128) bf16, gate-sign folded
    const float* __restrict__ bias,  // 512, gate-sign folded
    short* h_out,                    // (B,T,128) bf16 or null (may alias h_in)
    float* __restrict__ fout)        // (B,128) f32 or null
{
    __shared__ short h_lds[2 * 8 * HP];          // 4.25 KB
    __shared__ float xp_lds[2 * G_DIM * XPR];    // 48 KB
    __shared__ float rc_lds[G_DIM * XPR];        // 24 KB

    const int tid = threadIdx.x;
    const int w = tid >> 6, lane = tid & 63;
    const int m16 = lane & 15, q = lane >> 4, m8 = m16 & 7;
    const int dl = m16, rp = q;                  // update mapping: dim-local, row-pair
    const int b0 = blockIdx.x * 8;

    for (int i = tid; i < 8 * HP; i += 512) ((unsigned*)h_lds)[i] = 0u;

    // weights: per gate one 16-wide n-tile, 4 k-chunks; whh + wih = 128 VGPR
    short8 whf[4][4], wif[4][4];
    float bias_v[4];
#pragma unroll
    for (int g = 0; g < 4; ++g) {
        int n = g * 128 + w * 16 + m16;
        bias_v[g] = bias[n];
#pragma unroll
        for (int kc = 0; kc < 4; ++kc) {
            whf[g][kc] = *(const short8*)(whh + n * H_DIM + kc * 32 + q * 8);
            wif[g][kc] = *(const short8*)(wih + n * H_DIM + kc * 32 + q * 8);
        }
    }

    float c0 = 0.f, c1 = 0.f;                    // cell state, rows 2rp, 2rp+1

    auto loadA = [&](short8 ax[4], int t) {
        const short* src = h_in + ((size_t)(b0 + m8) * T_STEPS + t) * H_DIM + q * 8;
#pragma unroll
        for (int kc = 0; kc < 4; ++kc) ax[kc] = *(const short8*)(src + kc * 32);
    };
    auto prodMFMA = [&](short8 ax[4], int t) {
        float* xpb = xp_lds + (t & 1) * (G_DIM * XPR);
#pragma unroll
        for (int g = 0; g < 4; ++g) {
            float bv = bias_v[g];
            f32x4 acc = (f32x4){bv, bv, bv, bv};
#pragma unroll
            for (int kc = 0; kc < 4; ++kc) acc = mfma16(ax[kc], wif[g][kc], acc);
            if (q < 2)
                *(f32x4*)(xpb + (g * 128 + w * 16 + m16) * XPR + q * 4) = acc;
        }
    };

    // prologue: xp(0)
    {
        short8 ax[4];
        loadA(ax, 0);
        prodMFMA(ax, 0);
    }
    __syncthreads();

    for (int s = 0; s < T_STEPS; ++s) {
        // prefetch next input-proj A-fragments (hide HBM latency behind rec)
        short8 ax[4];
        if (s + 1 < T_STEPS) loadA(ax, s + 1);

        // recurrent matmul on h(s-1)
        {
            const short* hb = h_lds + ((s + 1) & 1) * (8 * HP) + m8 * HP + q * 8;
            short8 ar[4];
#pragma unroll
            for (int kc = 0; kc < 4; ++kc) ar[kc] = *(const short8*)(hb + kc * 32);
#pragma unroll
            for (int g = 0; g < 4; ++g) {
                f32x4 acc = (f32x4){0.f, 0.f, 0.f, 0.f};
#pragma unroll
                for (int kc = 0; kc < 4; ++kc) acc = mfma16(ar[kc], whf[g][kc], acc);
                if (q < 2)
                    *(f32x4*)(rc_lds + (g * 128 + w * 16 + m16) * XPR + q * 4) = acc;
            }
        }

        if (s + 1 < T_STEPS) prodMFMA(ax, s + 1);

        // update: 2 elements per lane (dim = 16w+dl, rows 2rp, 2rp+1)
        {
            const float* xpb = xp_lds + (s & 1) * (G_DIM * XPR);
            float2 rd[4], xd[4];
#pragma unroll
            for (int g = 0; g < 4; ++g) {
                int n = (g * 128 + w * 16 + dl) * XPR + rp * 2;
                rd[g] = *(const float2*)(rc_lds + n);
                xd[g] = *(const float2*)(xpb + n);
            }
            float i0 = sig_y(rd[0].x + xd[0].x), i1 = sig_y(rd[0].y + xd[0].y);
            float f0 = sig_y(rd[1].x + xd[1].x), f1 = sig_y(rd[1].y + xd[1].y);
            float g0 = tanh_y(rd[2].x + xd[2].x), g1 = tanh_y(rd[2].y + xd[2].y);
            float o0 = sig_y(rd[3].x + xd[3].x), o1 = sig_y(rd[3].y + xd[3].y);
            c0 = f0 * c0 + i0 * g0;
            c1 = f1 * c1 + i1 * g1;
            float h0v = o0 * tanh_y(2.f * c0);
            float h1v = o1 * tanh_y(2.f * c1);

            short* hw = h_lds + (s & 1) * (8 * HP);
            int dim = w * 16 + dl;
            hw[(rp * 2) * HP + dim]     = f2bf(h0v);
            hw[(rp * 2 + 1) * HP + dim] = f2bf(h1v);
            if (fout != nullptr && s == T_STEPS - 1) {
                fout[(size_t)(b0 + rp * 2) * H_DIM + dim]     = h0v;
                fout[(size_t)(b0 + rp * 2 + 1) * H_DIM + dim] = h1v;
            }
        }

        // coalesced export of h(s-1) (written one barrier ago)
        if (h_out != nullptr && s >= 1) {
            int row = tid >> 6, c2 = tid & 63;
            unsigned v = ((const unsigned*)h_lds)[((s + 1) & 1) * (4 * HP) + row * (HP / 2) + c2];
            ((unsigned*)h_out)[((size_t)(b0 + row) * T_STEPS + (s - 1)) * (H_DIM / 2) + c2] = v;
        }
        __syncthreads();
    }
    if (h_out != nullptr) {   // tail: h(T-1) is in buffer (T-1)&1 = 1
        int row = tid >> 6, c2 = tid & 63;
        unsigned v = ((const unsigned*)h_lds)[1 * (4 * HP) + row * (HP / 2) + c2];
        ((unsigned*)h_out)[((size_t)(b0 + row) * T_STEPS + (T_STEPS - 1)) * (H_DIM / 2) + c2] = v;
    }
}

// ---------------- launch ----------------
static constexpr size_t OFF_FCW  = 0;        // 128*192*2 = 49152
static constexpr size_t OFF_FCB  = 49152;    // 128*4
static constexpr size_t OFF_B0   = 49664;    // 512*4
static constexpr size_t OFF_B1   = 51712;    // 512*4
static constexpr size_t OFF_WIH0 = 53760;    // 512*128*2
static constexpr size_t OFF_WHH0 = 184832;
static constexpr size_t OFF_WIH1 = 315904;
static constexpr size_t OFF_WHH1 = 446976;
static constexpr size_t OFF_BUFA = 578048;   // B*T*128*2 = 62914560

extern "C" void kernel_launch(void* const* d_in, const int* in_sizes, int n_in,
                              void* d_out, int out_size, void* d_ws, size_t ws_size,
                              hipStream_t stream) {
    const float* x       = (const float*)d_in[0];
    const float* fc_w    = (const float*)d_in[1];
    const float* fc_b    = (const float*)d_in[2];
    const float* bn_g    = (const float*)d_in[3];
    const float* bn_b    = (const float*)d_in[4];
    const float* bn_mean = (const float*)d_in[5];
    const float* bn_var  = (const float*)d_in[6];
    const float* wih0    = (const float*)d_in[7];
    const float* whh0    = (const float*)d_in[8];
    const float* bih0    = (const float*)d_in[9];
    const float* bhh0    = (const float*)d_in[10];
    const float* wih1    = (const float*)d_in[11];
    const float* whh1    = (const float*)d_in[12];
    const float* bih1    = (const float*)d_in[13];
    const float* bhh1    = (const float*)d_in[14];

    const int B = in_sizes[0] / (NF_IN * T_STEPS);   // 2048

    char* ws = (char*)d_ws;
    short* fcw   = (short*)(ws + OFF_FCW);
    float* fcb   = (float*)(ws + OFF_FCB);
    float* bias0 = (float*)(ws + OFF_B0);
    float* bias1 = (float*)(ws + OFF_B1);
    short* wih0b = (short*)(ws + OFF_WIH0);
    short* whh0b = (short*)(ws + OFF_WHH0);
    short* wih1b = (short*)(ws + OFF_WIH1);
    short* whh1b = (short*)(ws + OFF_WHH1);
    short* bufA  = (short*)(ws + OFF_BUFA);

    prep_kernel<<<256, 256, 0, stream>>>(
        fc_w, fc_b, bn_g, bn_b, bn_mean, bn_var,
        wih0, whh0, bih0, bhh0, wih1, whh1, bih1, bhh1,
        fcw, fcb, bias0, bias1, wih0b, whh0b, wih1b, whh1b);

    fc_kernel<<<B, 256, 0, stream>>>(x, fcw, fcb, bufA);

    // layer 0: in-place on bufA (export write of t=s-1 trails prefetch read of t=s+1)
    lstm_kernel<<<B / 8, 512, 0, stream>>>(bufA, wih0b, whh0b, bias0, bufA, nullptr);
    // layer 1: final hidden only
    lstm_kernel<<<B / 8, 512, 0, stream>>>(bufA, wih1b, whh1b, bias1, nullptr, (float*)d_out);
}

// Round 4
// 595.351 us; speedup vs baseline: 1.2264x; 1.2264x over previous
//
#include <hip/hip_runtime.h>

#define T_STEPS 120
#define NF_IN   180
#define H_DIM   128
#define G_DIM   512
#define K_FC    192
#define HP      136   // h_lds row stride (shorts)
#define XPR     12    // xp/racc row stride (floats)

typedef __attribute__((ext_vector_type(8))) short short8;
typedef __attribute__((ext_vector_type(4))) float f32x4;

// barrier WITHOUT vmcnt drain: LDS-ordering only. Global loads/stores stay in
// flight across steps (HIP __syncthreads drains vmcnt(0) -> ~900cyc/step stall).
#define LDS_BARRIER() asm volatile("s_waitcnt lgkmcnt(0)\ns_barrier" ::: "memory")

__device__ __forceinline__ f32x4 mfma16(short8 a, short8 b, f32x4 c) {
    return __builtin_amdgcn_mfma_f32_16x16x32_bf16(a, b, c, 0, 0, 0);
}

__device__ __forceinline__ short f2bf(float x) {
    union { float f; unsigned u; } v; v.f = x;
    unsigned r = v.u + 0x7fffu + ((v.u >> 16) & 1u);
    return (short)(r >> 16);
}

// gate-sign folded weights: i,f,o rows *-1 (sigmoid(x)=rcp(1+exp(y))), g rows *+2
__device__ __forceinline__ float sig_y(float y) {
    return __builtin_amdgcn_rcpf(1.f + __expf(y));
}
__device__ __forceinline__ float tanh_y(float y) {
    return 1.f - 2.f * __builtin_amdgcn_rcpf(1.f + __expf(y));
}

// ---------------- K1: weight prep (BN fold + bf16 + gate-sign folding) -------
__global__ void prep_kernel(
    const float* __restrict__ fc_w, const float* __restrict__ fc_b,
    const float* __restrict__ bn_g, const float* __restrict__ bn_b,
    const float* __restrict__ bn_mean, const float* __restrict__ bn_var,
    const float* __restrict__ wih0, const float* __restrict__ whh0,
    const float* __restrict__ bih0, const float* __restrict__ bhh0,
    const float* __restrict__ wih1, const float* __restrict__ whh1,
    const float* __restrict__ bih1, const float* __restrict__ bhh1,
    short* __restrict__ fcw_o, float* __restrict__ fcb_o,
    float* __restrict__ bias0_o, float* __restrict__ bias1_o,
    short* __restrict__ wih0_o, short* __restrict__ whh0_o,
    short* __restrict__ wih1_o, short* __restrict__ whh1_o)
{
    int tid = blockIdx.x * blockDim.x + threadIdx.x;
    int stride = gridDim.x * blockDim.x;
    for (int i = tid; i < H_DIM * K_FC; i += stride) {
        int h = i / K_FC, f = i % K_FC;
        float s = bn_g[h] * rsqrtf(bn_var[h] + 1e-5f);
        float v = (f < NF_IN) ? fc_w[h * NF_IN + f] * s : 0.f;
        fcw_o[i] = f2bf(v);
    }
    for (int i = tid; i < H_DIM; i += stride) {
        float s = bn_g[i] * rsqrtf(bn_var[i] + 1e-5f);
        fcb_o[i] = (fc_b[i] - bn_mean[i]) * s + bn_b[i];
    }
    for (int i = tid; i < G_DIM; i += stride) {
        float sc = ((i >> 7) == 2) ? 2.f : -1.f;
        bias0_o[i] = (bih0[i] + bhh0[i]) * sc;
        bias1_o[i] = (bih1[i] + bhh1[i]) * sc;
    }
    for (int i = tid; i < G_DIM * H_DIM; i += stride) {
        float sc = ((i >> 7) / H_DIM == 2) ? 2.f : -1.f;
        wih0_o[i] = f2bf(wih0[i] * sc); whh0_o[i] = f2bf(whh0[i] * sc);
        wih1_o[i] = f2bf(wih1[i] * sc); whh1_o[i] = f2bf(whh1[i] * sc);
    }
}

// ---------------- K2: fused FC + BN + LeakyReLU ------------------------------
__global__ __launch_bounds__(256) void fc_kernel(
    const float* __restrict__ x, const short* __restrict__ fcw,
    const float* __restrict__ fcb, short* __restrict__ xfc)
{
    __shared__ short outs[120 * 132];
    const int b = blockIdx.x;
    const int tid = threadIdx.x;
    const int wave = tid >> 6, lane = tid & 63;
    const int m16 = lane & 15, q = lane >> 4;

    short8 af[2][6];
#pragma unroll
    for (int mi = 0; mi < 2; ++mi) {
        int t = (wave * 2 + mi) * 16 + m16;
        if (t > 119) t = 119;
        const float* xb = x + (size_t)b * (NF_IN * T_STEPS) + (size_t)q * 8 * T_STEPS + t;
#pragma unroll
        for (int kc = 0; kc < 6; ++kc) {
            union { short s[8]; short8 v; } u;
#pragma unroll
            for (int j = 0; j < 8; ++j) {
                int f = kc * 32 + q * 8 + j;
                float val = (f < NF_IN) ? xb[(kc * 32 + j) * T_STEPS] : 0.f;
                u.s[j] = f2bf(val);
            }
            af[mi][kc] = u.v;
        }
    }

    float fcb_v[8];
#pragma unroll
    for (int nt = 0; nt < 8; ++nt) fcb_v[nt] = fcb[nt * 16 + m16];

    f32x4 acc[2][8];
#pragma unroll
    for (int mi = 0; mi < 2; ++mi)
#pragma unroll
        for (int nt = 0; nt < 8; ++nt) acc[mi][nt] = (f32x4){0.f, 0.f, 0.f, 0.f};

#pragma unroll
    for (int nt = 0; nt < 8; ++nt) {
        short8 bf[6];
#pragma unroll
        for (int kc = 0; kc < 6; ++kc)
            bf[kc] = *(const short8*)(fcw + (nt * 16 + m16) * K_FC + kc * 32 + q * 8);
#pragma unroll
        for (int mi = 0; mi < 2; ++mi)
#pragma unroll
            for (int kc = 0; kc < 6; ++kc)
                acc[mi][nt] = mfma16(af[mi][kc], bf[kc], acc[mi][nt]);
    }

#pragma unroll
    for (int mi = 0; mi < 2; ++mi)
#pragma unroll
        for (int nt = 0; nt < 8; ++nt)
#pragma unroll
            for (int r = 0; r < 4; ++r) {
                int t = (wave * 2 + mi) * 16 + q * 4 + r;
                int h = nt * 16 + m16;
                float v = acc[mi][nt][r] + fcb_v[nt];
                v = (v >= 0.f) ? v : 0.01f * v;
                if (t < 120) outs[t * 132 + h] = f2bf(v);
            }
    __syncthreads();

    unsigned* dst = (unsigned*)xfc + (size_t)b * (T_STEPS * H_DIM / 2);
    const unsigned* srcs = (const unsigned*)outs;
    for (int i = tid; i < T_STEPS * H_DIM / 2; i += 256) {
        int t = i >> 6, c2 = i & 63;
        dst[i] = srcs[t * 66 + c2];
    }
}

// ---------------- K3: one LSTM layer -----------------------------------------
// 256 blocks x 512 thr (8 waves), 8 batch rows/block. Wave w owns dims
// [16w,16w+16) x 4 gates of BOTH matmuls (weights in VGPRs). Per 2 steps:
// 2x rec (M=8) + 1x proj (M=16: rows 0-7 = t1, 8-15 = t2). Proj runs AFTER
// update (slack-filling). LDS-only barriers; x prefetched 2 steps ahead.
__global__ __launch_bounds__(512, 2) void lstm_kernel(
    const short* h_in, const short* __restrict__ wih,
    const short* __restrict__ whh, const float* __restrict__ bias,
    short* h_out, float* __restrict__ fout)
{
    __shared__ short h_lds[2 * 8 * HP];
    __shared__ float xp_lds[2 * G_DIM * XPR];
    __shared__ float rc_lds[G_DIM * XPR];

    const int tid = threadIdx.x;
    const int w = tid >> 6, lane = tid & 63;
    const int m16 = lane & 15, q = lane >> 4, m8 = m16 & 7;
    const int b0 = blockIdx.x * 8;

    for (int i = tid; i < 8 * HP; i += 512) ((unsigned*)h_lds)[i] = 0u;

    short8 whf[4][4], wif[4][4];
    float bias_v[4];
#pragma unroll
    for (int g = 0; g < 4; ++g) {
        int n = g * 128 + w * 16 + m16;
        bias_v[g] = bias[n];
#pragma unroll
        for (int kc = 0; kc < 4; ++kc) {
            whf[g][kc] = *(const short8*)(whh + n * H_DIM + kc * 32 + q * 8);
            wif[g][kc] = *(const short8*)(wih + n * H_DIM + kc * 32 + q * 8);
        }
    }

    float c0 = 0.f, c1 = 0.f;

    // pair-load A-frags for proj(t1, t1+1): rows 0-7 <- t1, rows 8-15 <- t1+1
    auto loadPair = [&](short8 ax[4], int t1) {
        int t = t1 + (m16 >> 3);
        if (t > T_STEPS - 1) t = T_STEPS - 1;
        const short* src = h_in + ((size_t)(b0 + m8) * T_STEPS + t) * H_DIM + q * 8;
#pragma unroll
        for (int kc = 0; kc < 4; ++kc) ax[kc] = *(const short8*)(src + kc * 32);
    };

    // rec matmul: h(s-1) from buffer rb -> rc_lds
    auto recStep = [&](int rb) {
        const short* hb = h_lds + rb * (8 * HP) + m8 * HP + q * 8;
        short8 ar[4];
#pragma unroll
        for (int kc = 0; kc < 4; ++kc) ar[kc] = *(const short8*)(hb + kc * 32);
#pragma unroll
        for (int g = 0; g < 4; ++g) {
            f32x4 acc = (f32x4){0.f, 0.f, 0.f, 0.f};
#pragma unroll
            for (int kc = 0; kc < 4; ++kc) acc = mfma16(ar[kc], whf[g][kc], acc);
            if (q < 2)
                *(f32x4*)(rc_lds + (g * 128 + w * 16 + m16) * XPR + q * 4) = acc;
        }
    };

    // gate/cell update for step s: xp from buffer xb, h(s) -> buffer hb
    auto update = [&](int s, int xb, int hb) {
        const float* xpb = xp_lds + xb * (G_DIM * XPR);
        float2 rd[4], xd[4];
#pragma unroll
        for (int g = 0; g < 4; ++g) {
            int n = (g * 128 + w * 16 + m16) * XPR + q * 2;
            rd[g] = *(const float2*)(rc_lds + n);
            xd[g] = *(const float2*)(xpb + n);
        }
        float i0 = sig_y(rd[0].x + xd[0].x), i1 = sig_y(rd[0].y + xd[0].y);
        float f0 = sig_y(rd[1].x + xd[1].x), f1 = sig_y(rd[1].y + xd[1].y);
        float g0 = tanh_y(rd[2].x + xd[2].x), g1 = tanh_y(rd[2].y + xd[2].y);
        float o0 = sig_y(rd[3].x + xd[3].x), o1 = sig_y(rd[3].y + xd[3].y);
        c0 = f0 * c0 + i0 * g0;
        c1 = f1 * c1 + i1 * g1;
        float h0v = o0 * tanh_y(2.f * c0);
        float h1v = o1 * tanh_y(2.f * c1);
        short* hw = h_lds + hb * (8 * HP);
        int dim = w * 16 + m16;
        hw[(q * 2) * HP + dim]     = f2bf(h0v);
        hw[(q * 2 + 1) * HP + dim] = f2bf(h1v);
        if (fout != nullptr && s == T_STEPS - 1) {
            fout[(size_t)(b0 + q * 2) * H_DIM + dim]     = h0v;
            fout[(size_t)(b0 + q * 2 + 1) * H_DIM + dim] = h1v;
        }
    };

    // proj for pair (t1, t1+1), M=16 fully used; lane rows q*4..q*4+3:
    // q<2 -> t1 (xp buf t1&1), q>=2 -> t1+1 (buf (t1+1)&1); row-in-step (q&1)*4
    auto projPair = [&](short8 ax[4], int t1) {
        float* xpb = xp_lds + ((t1 + (q >> 1)) & 1) * (G_DIM * XPR);
#pragma unroll
        for (int g = 0; g < 4; ++g) {
            float bv = bias_v[g];
            f32x4 acc = (f32x4){bv, bv, bv, bv};
#pragma unroll
            for (int kc = 0; kc < 4; ++kc) acc = mfma16(ax[kc], wif[g][kc], acc);
            *(f32x4*)(xpb + (g * 128 + w * 16 + m16) * XPR + (q & 1) * 4) = acc;
        }
    };

    auto exportH = [&](int s, int hb) {   // coalesced h(s) -> global
        int row = tid >> 6, c2 = tid & 63;
        unsigned v = ((const unsigned*)h_lds)[hb * (4 * HP) + row * (HP / 2) + c2];
        ((unsigned*)h_out)[((size_t)(b0 + row) * T_STEPS + s) * (H_DIM / 2) + c2] = v;
    };

    // prologue: xp(0) (M=8, rows m8 at t=0), prefetch pair (1,2)
    {
        short8 a0[4];
        const short* src = h_in + (size_t)(b0 + m8) * T_STEPS * H_DIM + q * 8;
#pragma unroll
        for (int kc = 0; kc < 4; ++kc) a0[kc] = *(const short8*)(src + kc * 32);
#pragma unroll
        for (int g = 0; g < 4; ++g) {
            float bv = bias_v[g];
            f32x4 acc = (f32x4){bv, bv, bv, bv};
#pragma unroll
            for (int kc = 0; kc < 4; ++kc) acc = mfma16(a0[kc], wif[g][kc], acc);
            if (q < 2)
                *(f32x4*)(xp_lds + (g * 128 + w * 16 + m16) * XPR + q * 4) = acc;
        }
    }
    short8 axc[4];
    loadPair(axc, 1);
    LDS_BARRIER();

    for (int it = 0; it < T_STEPS / 2; ++it) {
        const int s = 2 * it;
        // ---- even step: rec + update + proj(s+1,s+2) + prefetch(s+3,s+4) ----
        short8 axn[4];
        loadPair(axn, s + 3);
        recStep(1);                 // h(s-1) in buf1
        update(s, 0, 0);            // xp buf0, h(s) -> buf0
        projPair(axc, s + 1);       // xp(s+1)->buf1, xp(s+2)->buf0
        if (h_out != nullptr && s >= 1) exportH(s - 1, 1);
        LDS_BARRIER();
        // ---- odd step: rec + update ----
        recStep(0);                 // h(s) in buf0
        update(s + 1, 1, 1);        // xp buf1, h(s+1) -> buf1
#pragma unroll
        for (int kc = 0; kc < 4; ++kc) axc[kc] = axn[kc];
        if (h_out != nullptr) exportH(s, 0);
        LDS_BARRIER();
    }
    if (h_out != nullptr) exportH(T_STEPS - 1, 1);
}

// ---------------- launch ----------------
static constexpr size_t OFF_FCW  = 0;
static constexpr size_t OFF_FCB  = 49152;
static constexpr size_t OFF_B0   = 49664;
static constexpr size_t OFF_B1   = 51712;
static constexpr size_t OFF_WIH0 = 53760;
static constexpr size_t OFF_WHH0 = 184832;
static constexpr size_t OFF_WIH1 = 315904;
static constexpr size_t OFF_WHH1 = 446976;
static constexpr size_t OFF_BUFA = 578048;

extern "C" void kernel_launch(void* const* d_in, const int* in_sizes, int n_in,
                              void* d_out, int out_size, void* d_ws, size_t ws_size,
                              hipStream_t stream) {
    const float* x       = (const float*)d_in[0];
    const float* fc_w    = (const float*)d_in[1];
    const float* fc_b    = (const float*)d_in[2];
    const float* bn_g    = (const float*)d_in[3];
    const float* bn_b    = (const float*)d_in[4];
    const float* bn_mean = (const float*)d_in[5];
    const float* bn_var  = (const float*)d_in[6];
    const float* wih0    = (const float*)d_in[7];
    const float* whh0    = (const float*)d_in[8];
    const float* bih0    = (const float*)d_in[9];
    const float* bhh0    = (const float*)d_in[10];
    const float* wih1    = (const float*)d_in[11];
    const float* whh1    = (const float*)d_in[12];
    const float* bih1    = (const float*)d_in[13];
    const float* bhh1    = (const float*)d_in[14];

    const int B = in_sizes[0] / (NF_IN * T_STEPS);   // 2048

    char* ws = (char*)d_ws;
    short* fcw   = (short*)(ws + OFF_FCW);
    float* fcb   = (float*)(ws + OFF_FCB);
    float* bias0 = (float*)(ws + OFF_B0);
    float* bias1 = (float*)(ws + OFF_B1);
    short* wih0b = (short*)(ws + OFF_WIH0);
    short* whh0b = (short*)(ws + OFF_WHH0);
    short* wih1b = (short*)(ws + OFF_WIH1);
    short* whh1b = (short*)(ws + OFF_WHH1);
    short* bufA  = (short*)(ws + OFF_BUFA);

    prep_kernel<<<256, 256, 0, stream>>>(
        fc_w, fc_b, bn_g, bn_b, bn_mean, bn_var,
        wih0, whh0, bih0, bhh0, wih1, whh1, bih1, bhh1,
        fcw, fcb, bias0, bias1, wih0b, whh0b, wih1b, whh1b);

    fc_kernel<<<B, 256, 0, stream>>>(x, fcw, fcb, bufA);

    lstm_kernel<<<B / 8, 512, 0, stream>>>(bufA, wih0b, whh0b, bias0, bufA, nullptr);
    lstm_kernel<<<B / 8, 512, 0, stream>>>(bufA, wih1b, whh1b, bias1, nullptr, (float*)d_out);
}